// Round 3
// baseline (195.453 us; speedup 1.0000x reference)
//
#include <hip/hip_runtime.h>
#include <stdint.h>

// CoefficientMaxPool: x [B=32, N=512, IR=16, C=128] f32.
// ll2[b,n,l,c] = sum_{i in degree l} x[b,n,i,c]^2 ; win[b,l,c] = argmax_n ll2
// out[b,i,c] = x[b, win[b,l(i),c], i, c]
//
// Two-phase argmax over n, no atomics. Packed (value_bits<<32 | ~n) u64:
// ll2 >= 0 so float bits are order-isomorphic; ~n breaks ties toward the
// SMALLEST n (first occurrence), matching jnp.argmax. Sum over i is ascending,
// same as the einsum -> bit-identical f32 values (absmax 0.0 verified R1/R2).
//
// R3: phase1 re-tuned for TLP: 256-thr blocks, 1 neighbor/thread (16
// independent float4 loads), 2048 blocks (~32 waves/CU launched), shuffle +
// 16 KiB LDS reduction.

constexpr int B_  = 32;
constexpr int N_  = 512;
constexpr int IR_ = 16;
constexpr int C_  = 128;
constexpr int NL_ = 4;
constexpr int E_  = NL_ * C_;        // 512 entries per b

constexpr int NCHUNK = 64;           // n-chunks (grid.x)
constexpr int CHN    = N_ / NCHUNK;  // 8 n per chunk = 1 per thread

// irrep index -> degree l (LMAX=3, fixed by the reference setup)
__device__ constexpr int L_OF_I[16] = {0, 1,1,1, 2,2,2,2,2, 3,3,3,3,3,3,3};
__device__ constexpr int I0_OF_L[4] = {0, 1, 4, 9};   // first irrep of degree l
__device__ constexpr int NI_OF_L[4] = {1, 3, 5, 7};   // 2l+1

__global__ __launch_bounds__(256)
void cmp_phase1(const float* __restrict__ x, unsigned long long* __restrict__ ws) {
    const int t    = threadIdx.x;
    const int c4   = t & 31;     // float4 column group: c in [4*c4, 4*c4+4)
    const int nrow = t >> 5;     // neighbor sub-index in chunk, [0,8)
    const int wv   = t >> 6;     // wave id [0,4)
    const int chunk = blockIdx.x;
    const int b     = blockIdx.y;

    const int n = chunk * CHN + nrow;
    // float4-unit base index: ((b*N + n)*IR)*32 + c4  (fits in 32 bits)
    const float4* __restrict__ p = (const float4*)x + ((unsigned)(b * N_ + n) * IR_) * 32u + c4;

    float4 acc[NL_];
#pragma unroll
    for (int l = 0; l < NL_; ++l) { acc[l].x = acc[l].y = acc[l].z = acc[l].w = 0.f; }

#pragma unroll
    for (int i = 0; i < IR_; ++i) {
        const float4 v = p[i * 32];
        const int l = L_OF_I[i];            // compile-time under full unroll
        acc[l].x += v.x * v.x;
        acc[l].y += v.y * v.y;
        acc[l].z += v.z * v.z;
        acc[l].w += v.w * v.w;
    }

    const unsigned long long code = (unsigned long long)(~(unsigned int)n);
    unsigned long long best[NL_ * 4];
#pragma unroll
    for (int l = 0; l < NL_; ++l) {
        const float vals[4] = {acc[l].x, acc[l].y, acc[l].z, acc[l].w};
#pragma unroll
        for (int j = 0; j < 4; ++j)
            best[l * 4 + j] = ((unsigned long long)__float_as_uint(vals[j]) << 32) | code;
    }

    // Pair-reduce the two nrows within each wave (lanes t and t^32 share c4).
#pragma unroll
    for (int e = 0; e < NL_ * 4; ++e) {
        const unsigned long long q = __shfl_xor(best[e], 32, 64);
        if (q > best[e]) best[e] = q;
    }

    // One row per wave in LDS; lower half-wave holds the reduced pair.
    __shared__ unsigned long long red[4][E_];   // 16 KiB
    if ((t & 32) == 0) {
#pragma unroll
        for (int l = 0; l < NL_; ++l)
#pragma unroll
            for (int j = 0; j < 4; ++j)
                red[wv][l * C_ + c4 * 4 + j] = best[l * 4 + j];
    }
    __syncthreads();

    unsigned long long* __restrict__ wsp = ws + ((long)chunk * B_ + b) * E_;
#pragma unroll
    for (int k = 0; k < 2; ++k) {
        const int e = t + k * 256;               // entry in [0, E_)
        unsigned long long m = red[0][e];
#pragma unroll
        for (int w = 1; w < 4; ++w) {
            const unsigned long long v = red[w][e];
            if (v > m) m = v;
        }
        wsp[e] = m;                               // coalesced, contention-free
    }
}

// grid: (B_, NL_) x 128 threads. Thread = (b, l, c). Reduce 64 chunks,
// decode winner n, gather the 2l+1 irrep rows of degree l.
__global__ __launch_bounds__(128)
void cmp_phase2(const float* __restrict__ x,
                const unsigned long long* __restrict__ ws,
                float* __restrict__ out) {
    const int c = threadIdx.x;
    const int b = blockIdx.x;
    const int l = blockIdx.y;
    const int e = l * C_ + c;

    unsigned long long m = 0ull;
#pragma unroll
    for (int chunk = 0; chunk < NCHUNK; ++chunk) {
        const unsigned long long v = ws[((long)chunk * B_ + b) * E_ + e];
        if (v > m) m = v;
    }
    const int n = (int)(~(unsigned int)(m & 0xFFFFFFFFull));

    const int i0 = I0_OF_L[l];
    const int ni = NI_OF_L[l];
    const long src = (((long)b * N_ + n) * IR_ + i0) * C_ + c;
    const long dst = ((long)b * IR_ + i0) * C_ + c;
#pragma unroll 7
    for (int k = 0; k < ni; ++k) {
        out[dst + (long)k * C_] = x[src + (long)k * C_];
    }
}

extern "C" void kernel_launch(void* const* d_in, const int* in_sizes, int n_in,
                              void* d_out, int out_size, void* d_ws, size_t ws_size,
                              hipStream_t stream) {
    const float* x = (const float*)d_in[0];
    // d_in[1] (i2l) is a fixed 0/1 indicator for LMAX=3 — hardcoded as L_OF_I.
    unsigned long long* ws = (unsigned long long*)d_ws;
    float* out = (float*)d_out;

    // ws[NCHUNK][B_][E_] = 8 MiB, fully written by phase1 before phase2 reads
    // it (same stream -> ordered). No memset, no atomics.
    dim3 g1(NCHUNK, B_);
    cmp_phase1<<<g1, 256, 0, stream>>>(x, ws);
    dim3 g2(B_, NL_);
    cmp_phase2<<<g2, 128, 0, stream>>>(x, ws, out);
}